// Round 2
// baseline (491.635 us; speedup 1.0000x reference)
//
#include <hip/hip_runtime.h>
#include <hip/hip_bf16.h>

// SimpleMultiheadAttention on gfx950 — round 2.
// Changes vs r1: global_load_lds(16B) + BK=64 + XOR-swizzled LDS in GEMMs;
// attention kernels parallelized over s (1024/2048 blocks vs 256);
// attn_main restructured per-i PV (no pc accumulator) with fp32 partials + reduce.

#define B_ 2
#define T_ 1024
#define E_ 1024
#define H_ 16
#define HD_ 64
#define BH_ 32

typedef float f32x4 __attribute__((ext_vector_type(4)));
typedef short bfrag __attribute__((ext_vector_type(8)));   // 8 x bf16

__device__ __forceinline__ unsigned short f2b(float f) {
  unsigned int u = __float_as_uint(f);
  u += 0x7fffu + ((u >> 16) & 1u);          // RNE (inputs finite)
  return (unsigned short)(u >> 16);
}

__device__ __forceinline__ void gl_lds16(const unsigned short* g, unsigned short* l) {
  __builtin_amdgcn_global_load_lds(
      (const __attribute__((address_space(1))) unsigned int*)g,
      (__attribute__((address_space(3))) unsigned int*)l, 16, 0, 0);
}

// ---------------------------------------------------------------- convert
struct CvtArgs { const float* src[10]; unsigned short* dst[10]; int n[10]; };

__global__ __launch_bounds__(256) void cvt_kernel(CvtArgs a) {
  const int z = blockIdx.y;
  const float* __restrict__ s = a.src[z];
  unsigned short* __restrict__ d = a.dst[z];
  const int n = a.n[z];
  const int stride = gridDim.x * 256 * 4;
  for (int i = (blockIdx.x * 256 + threadIdx.x) * 4; i < n; i += stride) {
    float4 v = *(const float4*)(s + i);
    ushort4 o;
    o.x = f2b(v.x); o.y = f2b(v.y); o.z = f2b(v.z); o.w = f2b(v.w);
    *(ushort4*)(d + i) = o;
  }
}

// ---------------------------------------------------------------- GEMM core (BK=64, global_load_lds, XOR swizzle)
// C[128x128] tile of A[M x 1024] * W[1024x1024]^T, both row-major [row][k] bf16.
// LDS[r][chunk c] (16B chunks) holds global chunk c ^ (r&7)  -> ds_read_b128 hits 8-cyc floor.
__device__ __forceinline__ void mm128_bk64(const unsigned short* __restrict__ A,
                                           const unsigned short* __restrict__ W,
                                           int m0, int n0,
                                           unsigned short* As, unsigned short* Bs,
                                           f32x4 acc[4][4]) {
  const int tid  = threadIdx.x;
  const int lane = tid & 63, w = tid >> 6;
  const int lrow = lane & 15, quad = lane >> 4;
  const int wm = (w >> 1) * 64, wn = (w & 1) * 64;
  const int srow = lane >> 3;                       // 0..7
  const int gcol = ((lane & 7) ^ srow) * 8;         // swizzled source chunk (elems)

  const unsigned short* gA = A + (size_t)(m0 + w * 32 + srow) * E_ + gcol;
  const unsigned short* gB = W + (size_t)(n0 + w * 32 + srow) * E_ + gcol;
  unsigned short* lA = As + (w * 32) * 64;
  unsigned short* lB = Bs + (w * 32) * 64;

  for (int k0 = 0; k0 < E_; k0 += 64) {
    __syncthreads();                                // prev iter's ds_reads done
#pragma unroll
    for (int q = 0; q < 4; q++) {
      gl_lds16(gA + (size_t)q * 8 * E_ + k0, lA + q * 8 * 64);
      gl_lds16(gB + (size_t)q * 8 * E_ + k0, lB + q * 8 * 64);
    }
    __syncthreads();                                // vmcnt(0) drain -> LDS ready
#pragma unroll
    for (int kk = 0; kk < 2; kk++) {
      bfrag af[4], bf_[4];
#pragma unroll
      for (int mt = 0; mt < 4; mt++) {
        const int r = wm + mt * 16 + lrow;
        af[mt] = *(const bfrag*)(As + r * 64 + (((kk * 4 + quad) ^ (r & 7)) * 8));
      }
#pragma unroll
      for (int nt = 0; nt < 4; nt++) {
        const int r = wn + nt * 16 + lrow;
        bf_[nt] = *(const bfrag*)(Bs + r * 64 + (((kk * 4 + quad) ^ (r & 7)) * 8));
      }
#pragma unroll
      for (int mt = 0; mt < 4; mt++)
#pragma unroll
        for (int nt = 0; nt < 4; nt++)
          acc[mt][nt] = __builtin_amdgcn_mfma_f32_16x16x32_bf16(af[mt], bf_[nt], acc[mt][nt], 0, 0, 0);
    }
  }
}

// ---------------------------------------------------------------- projections
struct ProjArgs {
  const unsigned short* X[5];
  const unsigned short* W[5];
  const float* bias[5];
  unsigned short* dst[5];
};

__global__ __launch_bounds__(256) void proj_kernel(ProjArgs pa) {
  __shared__ unsigned short As[128 * 64];
  __shared__ unsigned short Bs[128 * 64];
  const int z = blockIdx.z;
  const int m0 = blockIdx.y * 128, n0 = blockIdx.x * 128;
  f32x4 acc[4][4];
#pragma unroll
  for (int mt = 0; mt < 4; mt++)
#pragma unroll
    for (int nt = 0; nt < 4; nt++) acc[mt][nt] = (f32x4)0.f;

  mm128_bk64(pa.X[z], pa.W[z], m0, n0, As, Bs, acc);

  const int tid = threadIdx.x, lane = tid & 63, w = tid >> 6;
  const int lrow = lane & 15, quad = lane >> 4;
  const int wm = (w >> 1) * 64, wn = (w & 1) * 64;
  const float* __restrict__ bias = pa.bias[z];
  unsigned short* __restrict__ dst = pa.dst[z];
  float bv[4];
#pragma unroll
  for (int nt = 0; nt < 4; nt++) bv[nt] = bias[n0 + wn + nt * 16 + lrow];
#pragma unroll
  for (int mt = 0; mt < 4; mt++)
#pragma unroll
    for (int nt = 0; nt < 4; nt++)
#pragma unroll
      for (int ii = 0; ii < 4; ii++) {
        const int m = m0 + wm + mt * 16 + quad * 4 + ii;    // (b,t)
        const int n = n0 + wn + nt * 16 + lrow;             // (h,d)
        const float v = acc[mt][nt][ii] + bv[nt];
        const int b = m >> 10, t = m & 1023, h = n >> 6, dd = n & 63;
        size_t idx;
        if (z == 4)  // V transposed: [bh][d][t]
          idx = ((size_t)((b * H_ + h) * HD_ + dd)) * T_ + t;
        else         // Q/K: [bh][t][d]
          idx = ((size_t)((b * H_ + h) * T_ + t)) * HD_ + dd;
        dst[idx] = f2b(v);
      }
}

// ---------------------------------------------------------------- sum pass
// grid (8 t-tiles, 8 s-tiles, 32 bh); 4 waves in 2x2 over a 128x128 score tile.
__global__ __launch_bounds__(256) void attn_sums_kernel(
    const unsigned short* __restrict__ Q1, const unsigned short* __restrict__ Q2,
    const unsigned short* __restrict__ Q3, const unsigned short* __restrict__ Kh,
    float* __restrict__ sums) {
  const int tid = threadIdx.x, lane = tid & 63, w = tid >> 6;
  const int lrow = lane & 15, quad = lane >> 4;
  const int tw = w >> 1, sw = w & 1;
  const int bh = blockIdx.z;
  const int tb = blockIdx.x * 128 + tw * 64;
  const int sb = blockIdx.y * 128 + sw * 64;
  const size_t base = (size_t)bh * T_ * HD_;
  const unsigned short* Qs[3] = {Q1 + base, Q2 + base, Q3 + base};
  const unsigned short* Kb = Kh + base;

  bfrag bf_[2][4];
#pragma unroll
  for (int kk = 0; kk < 2; kk++)
#pragma unroll
    for (int nt = 0; nt < 4; nt++)
      bf_[kk][nt] = *(const bfrag*)(Kb + (size_t)(sb + nt * 16 + lrow) * HD_ + kk * 32 + quad * 8);

  float lsum[3];
#pragma unroll
  for (int i = 0; i < 3; i++) {
    f32x4 acc[4][4];
#pragma unroll
    for (int mt = 0; mt < 4; mt++)
#pragma unroll
      for (int nt = 0; nt < 4; nt++) acc[mt][nt] = (f32x4)0.f;
#pragma unroll
    for (int kk = 0; kk < 2; kk++) {
      bfrag af[4];
#pragma unroll
      for (int mt = 0; mt < 4; mt++)
        af[mt] = *(const bfrag*)(Qs[i] + (size_t)(tb + mt * 16 + lrow) * HD_ + kk * 32 + quad * 8);
#pragma unroll
      for (int mt = 0; mt < 4; mt++)
#pragma unroll
        for (int nt = 0; nt < 4; nt++)
          acc[mt][nt] = __builtin_amdgcn_mfma_f32_16x16x32_bf16(af[mt], bf_[kk][nt], acc[mt][nt], 0, 0, 0);
    }
    float s = 0.f;
#pragma unroll
    for (int mt = 0; mt < 4; mt++)
#pragma unroll
      for (int nt = 0; nt < 4; nt++)
#pragma unroll
        for (int ii = 0; ii < 4; ii++)
          s += __expf(acc[mt][nt][ii] * 0.25f);
    lsum[i] = s;
  }
#pragma unroll
  for (int i = 0; i < 3; i++) {
    float v = lsum[i];
    for (int off = 32; off > 0; off >>= 1) v += __shfl_down(v, off, 64);
    if (lane == 0) atomicAdd(&sums[i * BH_ + bh], v);
  }
}

// ---------------------------------------------------------------- main attention
// grid (8 t-tiles, 4 s-segments, 32 bh). Per-i PV: O += (r_i e_i) . V, fp32 partial per segment.
__global__ __launch_bounds__(256) void attn_main_kernel(
    const unsigned short* __restrict__ Q1, const unsigned short* __restrict__ Q2,
    const unsigned short* __restrict__ Q3, const unsigned short* __restrict__ Kh,
    const unsigned short* __restrict__ Vt, const float* __restrict__ sums,
    float* __restrict__ a1out, float* __restrict__ Opart) {
  __shared__ unsigned short P[128 * 136];   // stride 136: optimal bank rotation for b128
  const int tid = threadIdx.x, lane = tid & 63, w = tid >> 6;
  const int lrow = lane & 15, quad = lane >> 4;
  const int tw = w >> 1, sw = w & 1, dw = sw;
  const int bh = blockIdx.z;
  const int seg = blockIdx.y;
  const int tb = blockIdx.x * 128 + tw * 64;
  const size_t base = (size_t)bh * T_ * HD_;
  const unsigned short* Qs[3] = {Q1 + base, Q2 + base, Q3 + base};
  const unsigned short* Kb = Kh + base;
  const unsigned short* Vb = Vt + (size_t)bh * HD_ * T_;

  float r[3];
#pragma unroll
  for (int i = 0; i < 3; i++) r[i] = (float)T_ / (3.f * sums[i * BH_ + bh]);
  const float a1s = 3.f * r[0];

  f32x4 oacc[4][2];
#pragma unroll
  for (int mt = 0; mt < 4; mt++) { oacc[mt][0] = (f32x4)0.f; oacc[mt][1] = (f32x4)0.f; }

  for (int s0i = 0; s0i < 2; s0i++) {
    const int s0 = seg * 256 + s0i * 128;
    const int sb = s0 + sw * 64;
#pragma unroll
    for (int i = 0; i < 3; i++) {
      f32x4 acc[4][4];
#pragma unroll
      for (int mt = 0; mt < 4; mt++)
#pragma unroll
        for (int nt = 0; nt < 4; nt++) acc[mt][nt] = (f32x4)0.f;
#pragma unroll
      for (int kk = 0; kk < 2; kk++) {
        bfrag af[4], bf_[4];
#pragma unroll
        for (int mt = 0; mt < 4; mt++)
          af[mt] = *(const bfrag*)(Qs[i] + (size_t)(tb + mt * 16 + lrow) * HD_ + kk * 32 + quad * 8);
#pragma unroll
        for (int nt = 0; nt < 4; nt++)
          bf_[nt] = *(const bfrag*)(Kb + (size_t)(sb + nt * 16 + lrow) * HD_ + kk * 32 + quad * 8);
#pragma unroll
        for (int mt = 0; mt < 4; mt++)
#pragma unroll
          for (int nt = 0; nt < 4; nt++)
            acc[mt][nt] = __builtin_amdgcn_mfma_f32_16x16x32_bf16(af[mt], bf_[nt], acc[mt][nt], 0, 0, 0);
      }
      const float ri = r[i];
      __syncthreads();   // prev PV's ds_reads complete before overwrite
#pragma unroll
      for (int mt = 0; mt < 4; mt++)
#pragma unroll
        for (int nt = 0; nt < 4; nt++)
#pragma unroll
          for (int ii = 0; ii < 4; ii++) {
            const float e = __expf(acc[mt][nt][ii] * 0.25f);
            const int tl = tw * 64 + mt * 16 + quad * 4 + ii;
            const int sl = sw * 64 + nt * 16 + lrow;
            P[tl * 136 + sl] = f2b(ri * e);
            if (i == 0) {
              const int t = blockIdx.x * 128 + tl;
              a1out[((size_t)bh * T_ + t) * T_ + s0 + sl] = e * a1s;
            }
          }
      __syncthreads();   // P ready
      // PV: wave covers t[tw*64 .. +63] x d[dw*32 .. +31], K=128
#pragma unroll
      for (int kk = 0; kk < 4; kk++) {
        bfrag pf[4], vf[2];
#pragma unroll
        for (int mt = 0; mt < 4; mt++)
          pf[mt] = *(const bfrag*)(P + (tw * 64 + mt * 16 + lrow) * 136 + kk * 32 + quad * 8);
#pragma unroll
        for (int nt = 0; nt < 2; nt++)
          vf[nt] = *(const bfrag*)(Vb + (size_t)(dw * 32 + nt * 16 + lrow) * T_ + s0 + kk * 32 + quad * 8);
#pragma unroll
        for (int mt = 0; mt < 4; mt++)
#pragma unroll
          for (int nt = 0; nt < 2; nt++)
            oacc[mt][nt] = __builtin_amdgcn_mfma_f32_16x16x32_bf16(pf[mt], vf[nt], oacc[mt][nt], 0, 0, 0);
      }
    }
  }
  // partial O for this segment: Opart[seg][bh][t][d] fp32
  float* Ob = Opart + (size_t)seg * 2097152 + (size_t)bh * 65536;
#pragma unroll
  for (int mt = 0; mt < 4; mt++)
#pragma unroll
    for (int nt = 0; nt < 2; nt++)
#pragma unroll
      for (int ii = 0; ii < 4; ii++) {
        const int t = tb + mt * 16 + quad * 4 + ii;
        const int dd = dw * 32 + nt * 16 + lrow;
        Ob[(size_t)t * 64 + dd] = oacc[mt][nt][ii];
      }
}

// ---------------------------------------------------------------- partial reduce -> bf16 attn
__global__ __launch_bounds__(256) void reduce_kernel(const float* __restrict__ Op,
                                                     unsigned short* __restrict__ attn) {
  const int flat = blockIdx.x * 256 + threadIdx.x;   // 0..524287
  const int dq = (flat & 15) * 4;
  const int t  = (flat >> 4) & 1023;
  const int bh = flat >> 14;
  const int b = bh >> 4, h = bh & 15;
  const size_t poff = (size_t)bh * 65536 + (size_t)t * 64 + dq;
  float4 s0 = *(const float4*)(Op + poff);
  float4 s1 = *(const float4*)(Op + 2097152 + poff);
  float4 s2 = *(const float4*)(Op + 2 * 2097152 + poff);
  float4 s3 = *(const float4*)(Op + 3 * (size_t)2097152 + poff);
  ushort4 o;
  o.x = f2b(s0.x + s1.x + s2.x + s3.x);
  o.y = f2b(s0.y + s1.y + s2.y + s3.y);
  o.z = f2b(s0.z + s1.z + s2.z + s3.z);
  o.w = f2b(s0.w + s1.w + s2.w + s3.w);
  *(ushort4*)(attn + ((size_t)(b * T_ + t)) * E_ + h * HD_ + dq) = o;
}

// ---------------------------------------------------------------- output projection
__global__ __launch_bounds__(256) void outproj_kernel(
    const unsigned short* __restrict__ Ab, const unsigned short* __restrict__ Wb,
    const float* __restrict__ bias, float* __restrict__ out) {
  __shared__ unsigned short As[128 * 64];
  __shared__ unsigned short Bs[128 * 64];
  const int m0 = blockIdx.y * 128, n0 = blockIdx.x * 128;
  f32x4 acc[4][4];
#pragma unroll
  for (int mt = 0; mt < 4; mt++)
#pragma unroll
    for (int nt = 0; nt < 4; nt++) acc[mt][nt] = (f32x4)0.f;

  mm128_bk64(Ab, Wb, m0, n0, As, Bs, acc);

  const int tid = threadIdx.x, lane = tid & 63, w = tid >> 6;
  const int lrow = lane & 15, quad = lane >> 4;
  const int wm = (w >> 1) * 64, wn = (w & 1) * 64;
  float bv[4];
#pragma unroll
  for (int nt = 0; nt < 4; nt++) bv[nt] = bias[n0 + wn + nt * 16 + lrow];
#pragma unroll
  for (int mt = 0; mt < 4; mt++)
#pragma unroll
    for (int nt = 0; nt < 4; nt++)
#pragma unroll
      for (int ii = 0; ii < 4; ii++) {
        const int m = m0 + wm + mt * 16 + quad * 4 + ii;
        const int n = n0 + wn + nt * 16 + lrow;
        out[(size_t)m * E_ + n] = acc[mt][nt][ii] + bv[nt];
      }
}

// ---------------------------------------------------------------- launcher
extern "C" void kernel_launch(void* const* d_in, const int* in_sizes, int n_in,
                              void* d_out, int out_size, void* d_ws, size_t ws_size,
                              hipStream_t stream) {
  const float* q1f  = (const float*)d_in[0];
  const float* q2f  = (const float*)d_in[1];
  const float* keyf = (const float*)d_in[2];
  const float* valf = (const float*)d_in[3];
  const float* Wq  = (const float*)d_in[4];  const float* bq  = (const float*)d_in[5];
  const float* Wq2 = (const float*)d_in[6];  const float* bq2 = (const float*)d_in[7];
  const float* Wq3 = (const float*)d_in[8];  const float* bq3 = (const float*)d_in[9];
  const float* Wk  = (const float*)d_in[10]; const float* bk  = (const float*)d_in[11];
  const float* Wv  = (const float*)d_in[12]; const float* bv  = (const float*)d_in[13];
  const float* Wo  = (const float*)d_in[14]; const float* bo  = (const float*)d_in[15];

  char* ws = (char*)d_ws;
  const size_t MB = 1024 * 1024;
  unsigned short* xq1  = (unsigned short*)(ws + 0 * MB);
  unsigned short* xq2  = (unsigned short*)(ws + 4 * MB);
  unsigned short* xkey = (unsigned short*)(ws + 8 * MB);
  unsigned short* xval = (unsigned short*)(ws + 12 * MB);
  unsigned short* wq   = (unsigned short*)(ws + 16 * MB);
  unsigned short* wq2  = (unsigned short*)(ws + 18 * MB);
  unsigned short* wq3  = (unsigned short*)(ws + 20 * MB);
  unsigned short* wk   = (unsigned short*)(ws + 22 * MB);
  unsigned short* wv   = (unsigned short*)(ws + 24 * MB);
  unsigned short* wo   = (unsigned short*)(ws + 26 * MB);
  unsigned short* Qh1  = (unsigned short*)(ws + 28 * MB);
  unsigned short* Qh2  = (unsigned short*)(ws + 32 * MB);
  unsigned short* Qh3  = (unsigned short*)(ws + 36 * MB);
  unsigned short* Kh   = (unsigned short*)(ws + 40 * MB);
  unsigned short* Vt   = (unsigned short*)(ws + 44 * MB);
  unsigned short* attn = (unsigned short*)(ws + 48 * MB);
  float* Opart         = (float*)(ws + 52 * MB);           // 4 x 8MB fp32 partials
  float* sums          = (float*)(ws + 84 * MB);

  // 1) fp32 -> bf16
  CvtArgs ca;
  const float* srcs[10] = {q1f, q2f, keyf, valf, Wq, Wq2, Wq3, Wk, Wv, Wo};
  unsigned short* dsts[10] = {xq1, xq2, xkey, xval, wq, wq2, wq3, wk, wv, wo};
  for (int i = 0; i < 10; i++) { ca.src[i] = srcs[i]; ca.dst[i] = dsts[i]; ca.n[i] = (i < 4) ? 2097152 : 1048576; }
  cvt_kernel<<<dim3(2048, 10), 256, 0, stream>>>(ca);

  hipMemsetAsync(sums, 0, 3 * BH_ * sizeof(float), stream);

  // 2) projections -> head layouts (V transposed)
  ProjArgs pa;
  const unsigned short* Xs[5] = {xq1, xq2, xkey, xkey, xval};
  const unsigned short* Ws_[5] = {wq, wq2, wq3, wk, wv};
  const float* Bi[5] = {bq, bq2, bq3, bk, bv};
  unsigned short* Ds[5] = {Qh1, Qh2, Qh3, Kh, Vt};
  for (int i = 0; i < 5; i++) { pa.X[i] = Xs[i]; pa.W[i] = Ws_[i]; pa.bias[i] = Bi[i]; pa.dst[i] = Ds[i]; }
  proj_kernel<<<dim3(8, 16, 5), 256, 0, stream>>>(pa);

  // 3) global softmax denominators (2048 blocks)
  attn_sums_kernel<<<dim3(8, 8, BH_), 256, 0, stream>>>(Qh1, Qh2, Qh3, Kh, sums);

  // 4) attention: a1 + fp32 partial O per s-segment (1024 blocks)
  float* out = (float*)d_out;
  attn_main_kernel<<<dim3(8, 4, BH_), 256, 0, stream>>>(Qh1, Qh2, Qh3, Kh, Vt, sums,
                                                        out + 2097152, Opart);

  // 5) reduce partials -> bf16 attn
  reduce_kernel<<<dim3(2048), 256, 0, stream>>>(Opart, attn);

  // 6) output projection
  outproj_kernel<<<dim3(8, 16), 256, 0, stream>>>(attn, wo, bo, out);
}

// Round 3
// 405.022 us; speedup vs baseline: 1.2138x; 1.2138x over previous
//
#include <hip/hip_runtime.h>
#include <hip/hip_bf16.h>

// SimpleMultiheadAttention on gfx950 — round 3.
// Change vs r2: kill the device-scope atomicAdd storm in attn_sums (6144 RMWs
// onto 6 cache lines across 8 XCDs serialized -> 128us at 9% occupancy).
// attn_sums now writes per-block partials; attn_main butterfly-reduces them.

#define B_ 2
#define T_ 1024
#define E_ 1024
#define H_ 16
#define HD_ 64
#define BH_ 32

typedef float f32x4 __attribute__((ext_vector_type(4)));
typedef short bfrag __attribute__((ext_vector_type(8)));   // 8 x bf16

__device__ __forceinline__ unsigned short f2b(float f) {
  unsigned int u = __float_as_uint(f);
  u += 0x7fffu + ((u >> 16) & 1u);          // RNE (inputs finite)
  return (unsigned short)(u >> 16);
}

__device__ __forceinline__ void gl_lds16(const unsigned short* g, unsigned short* l) {
  __builtin_amdgcn_global_load_lds(
      (const __attribute__((address_space(1))) unsigned int*)g,
      (__attribute__((address_space(3))) unsigned int*)l, 16, 0, 0);
}

// ---------------------------------------------------------------- convert
struct CvtArgs { const float* src[10]; unsigned short* dst[10]; int n[10]; };

__global__ __launch_bounds__(256) void cvt_kernel(CvtArgs a) {
  const int z = blockIdx.y;
  const float* __restrict__ s = a.src[z];
  unsigned short* __restrict__ d = a.dst[z];
  const int n = a.n[z];
  const int stride = gridDim.x * 256 * 4;
  for (int i = (blockIdx.x * 256 + threadIdx.x) * 4; i < n; i += stride) {
    float4 v = *(const float4*)(s + i);
    ushort4 o;
    o.x = f2b(v.x); o.y = f2b(v.y); o.z = f2b(v.z); o.w = f2b(v.w);
    *(ushort4*)(d + i) = o;
  }
}

// ---------------------------------------------------------------- GEMM core (BK=64, global_load_lds, XOR swizzle)
__device__ __forceinline__ void mm128_bk64(const unsigned short* __restrict__ A,
                                           const unsigned short* __restrict__ W,
                                           int m0, int n0,
                                           unsigned short* As, unsigned short* Bs,
                                           f32x4 acc[4][4]) {
  const int tid  = threadIdx.x;
  const int lane = tid & 63, w = tid >> 6;
  const int lrow = lane & 15, quad = lane >> 4;
  const int wm = (w >> 1) * 64, wn = (w & 1) * 64;
  const int srow = lane >> 3;                       // 0..7
  const int gcol = ((lane & 7) ^ srow) * 8;         // swizzled source chunk (elems)

  const unsigned short* gA = A + (size_t)(m0 + w * 32 + srow) * E_ + gcol;
  const unsigned short* gB = W + (size_t)(n0 + w * 32 + srow) * E_ + gcol;
  unsigned short* lA = As + (w * 32) * 64;
  unsigned short* lB = Bs + (w * 32) * 64;

  for (int k0 = 0; k0 < E_; k0 += 64) {
    __syncthreads();                                // prev iter's ds_reads done
#pragma unroll
    for (int q = 0; q < 4; q++) {
      gl_lds16(gA + (size_t)q * 8 * E_ + k0, lA + q * 8 * 64);
      gl_lds16(gB + (size_t)q * 8 * E_ + k0, lB + q * 8 * 64);
    }
    __syncthreads();                                // vmcnt(0) drain -> LDS ready
#pragma unroll
    for (int kk = 0; kk < 2; kk++) {
      bfrag af[4], bf_[4];
#pragma unroll
      for (int mt = 0; mt < 4; mt++) {
        const int r = wm + mt * 16 + lrow;
        af[mt] = *(const bfrag*)(As + r * 64 + (((kk * 4 + quad) ^ (r & 7)) * 8));
      }
#pragma unroll
      for (int nt = 0; nt < 4; nt++) {
        const int r = wn + nt * 16 + lrow;
        bf_[nt] = *(const bfrag*)(Bs + r * 64 + (((kk * 4 + quad) ^ (r & 7)) * 8));
      }
#pragma unroll
      for (int mt = 0; mt < 4; mt++)
#pragma unroll
        for (int nt = 0; nt < 4; nt++)
          acc[mt][nt] = __builtin_amdgcn_mfma_f32_16x16x32_bf16(af[mt], bf_[nt], acc[mt][nt], 0, 0, 0);
    }
  }
}

// ---------------------------------------------------------------- projections
struct ProjArgs {
  const unsigned short* X[5];
  const unsigned short* W[5];
  const float* bias[5];
  unsigned short* dst[5];
};

__global__ __launch_bounds__(256) void proj_kernel(ProjArgs pa) {
  __shared__ unsigned short As[128 * 64];
  __shared__ unsigned short Bs[128 * 64];
  const int z = blockIdx.z;
  const int m0 = blockIdx.y * 128, n0 = blockIdx.x * 128;
  f32x4 acc[4][4];
#pragma unroll
  for (int mt = 0; mt < 4; mt++)
#pragma unroll
    for (int nt = 0; nt < 4; nt++) acc[mt][nt] = (f32x4)0.f;

  mm128_bk64(pa.X[z], pa.W[z], m0, n0, As, Bs, acc);

  const int tid = threadIdx.x, lane = tid & 63, w = tid >> 6;
  const int lrow = lane & 15, quad = lane >> 4;
  const int wm = (w >> 1) * 64, wn = (w & 1) * 64;
  const float* __restrict__ bias = pa.bias[z];
  unsigned short* __restrict__ dst = pa.dst[z];
  float bv[4];
#pragma unroll
  for (int nt = 0; nt < 4; nt++) bv[nt] = bias[n0 + wn + nt * 16 + lrow];
#pragma unroll
  for (int mt = 0; mt < 4; mt++)
#pragma unroll
    for (int nt = 0; nt < 4; nt++)
#pragma unroll
      for (int ii = 0; ii < 4; ii++) {
        const int m = m0 + wm + mt * 16 + quad * 4 + ii;    // (b,t)
        const int n = n0 + wn + nt * 16 + lrow;             // (h,d)
        const float v = acc[mt][nt][ii] + bv[nt];
        const int b = m >> 10, t = m & 1023, h = n >> 6, dd = n & 63;
        size_t idx;
        if (z == 4)  // V transposed: [bh][d][t]
          idx = ((size_t)((b * H_ + h) * HD_ + dd)) * T_ + t;
        else         // Q/K: [bh][t][d]
          idx = ((size_t)((b * H_ + h) * T_ + t)) * HD_ + dd;
        dst[idx] = f2b(v);
      }
}

// ---------------------------------------------------------------- sum pass
// grid (8 t, 8 s, 32 bh); per-block partial sums -> Sp[(i*32+bh)*64 + sy*8+tx].
__global__ __launch_bounds__(256) void attn_sums_kernel(
    const unsigned short* __restrict__ Q1, const unsigned short* __restrict__ Q2,
    const unsigned short* __restrict__ Q3, const unsigned short* __restrict__ Kh,
    float* __restrict__ Sp) {
  const int tid = threadIdx.x, lane = tid & 63, w = tid >> 6;
  const int lrow = lane & 15, quad = lane >> 4;
  const int tw = w >> 1, sw = w & 1;
  const int bh = blockIdx.z;
  const int tb = blockIdx.x * 128 + tw * 64;
  const int sb = blockIdx.y * 128 + sw * 64;
  const size_t base = (size_t)bh * T_ * HD_;
  const unsigned short* Qs[3] = {Q1 + base, Q2 + base, Q3 + base};
  const unsigned short* Kb = Kh + base;

  __shared__ float red[3][4];

  bfrag bf_[2][4];
#pragma unroll
  for (int kk = 0; kk < 2; kk++)
#pragma unroll
    for (int nt = 0; nt < 4; nt++)
      bf_[kk][nt] = *(const bfrag*)(Kb + (size_t)(sb + nt * 16 + lrow) * HD_ + kk * 32 + quad * 8);

#pragma unroll
  for (int i = 0; i < 3; i++) {
    f32x4 acc[4][4];
#pragma unroll
    for (int mt = 0; mt < 4; mt++)
#pragma unroll
      for (int nt = 0; nt < 4; nt++) acc[mt][nt] = (f32x4)0.f;
#pragma unroll
    for (int kk = 0; kk < 2; kk++) {
      bfrag af[4];
#pragma unroll
      for (int mt = 0; mt < 4; mt++)
        af[mt] = *(const bfrag*)(Qs[i] + (size_t)(tb + mt * 16 + lrow) * HD_ + kk * 32 + quad * 8);
#pragma unroll
      for (int mt = 0; mt < 4; mt++)
#pragma unroll
        for (int nt = 0; nt < 4; nt++)
          acc[mt][nt] = __builtin_amdgcn_mfma_f32_16x16x32_bf16(af[mt], bf_[kk][nt], acc[mt][nt], 0, 0, 0);
    }
    float s = 0.f;
#pragma unroll
    for (int mt = 0; mt < 4; mt++)
#pragma unroll
      for (int nt = 0; nt < 4; nt++)
#pragma unroll
        for (int ii = 0; ii < 4; ii++)
          s += __expf(acc[mt][nt][ii] * 0.25f);
    for (int off = 32; off > 0; off >>= 1) s += __shfl_down(s, off, 64);
    if (lane == 0) red[i][w] = s;
  }
  __syncthreads();
  if (tid < 3) {
    const float v = red[tid][0] + red[tid][1] + red[tid][2] + red[tid][3];
    Sp[((tid * BH_ + bh) << 6) + blockIdx.y * 8 + blockIdx.x] = v;   // plain store, no contention
  }
}

// ---------------------------------------------------------------- main attention
// grid (8 t, 4 s-segments, 32 bh). Reconstructs sums from Sp via 64-lane butterfly.
__global__ __launch_bounds__(256) void attn_main_kernel(
    const unsigned short* __restrict__ Q1, const unsigned short* __restrict__ Q2,
    const unsigned short* __restrict__ Q3, const unsigned short* __restrict__ Kh,
    const unsigned short* __restrict__ Vt, const float* __restrict__ Sp,
    float* __restrict__ a1out, float* __restrict__ Opart) {
  __shared__ unsigned short P[128 * 136];
  const int tid = threadIdx.x, lane = tid & 63, w = tid >> 6;
  const int lrow = lane & 15, quad = lane >> 4;
  const int tw = w >> 1, sw = w & 1, dw = sw;
  const int bh = blockIdx.z;
  const int seg = blockIdx.y;
  const int tb = blockIdx.x * 128 + tw * 64;
  const size_t base = (size_t)bh * T_ * HD_;
  const unsigned short* Qs[3] = {Q1 + base, Q2 + base, Q3 + base};
  const unsigned short* Kb = Kh + base;
  const unsigned short* Vb = Vt + (size_t)bh * HD_ * T_;

  float r[3];
#pragma unroll
  for (int i = 0; i < 3; i++) {
    float v = Sp[((i * BH_ + bh) << 6) + lane];      // 64 partials, one per lane
#pragma unroll
    for (int m = 1; m < 64; m <<= 1) v += __shfl_xor(v, m, 64);
    r[i] = (float)T_ / (3.f * v);
  }
  const float a1s = 3.f * r[0];

  f32x4 oacc[4][2];
#pragma unroll
  for (int mt = 0; mt < 4; mt++) { oacc[mt][0] = (f32x4)0.f; oacc[mt][1] = (f32x4)0.f; }

  for (int s0i = 0; s0i < 2; s0i++) {
    const int s0 = seg * 256 + s0i * 128;
    const int sb = s0 + sw * 64;
#pragma unroll
    for (int i = 0; i < 3; i++) {
      f32x4 acc[4][4];
#pragma unroll
      for (int mt = 0; mt < 4; mt++)
#pragma unroll
        for (int nt = 0; nt < 4; nt++) acc[mt][nt] = (f32x4)0.f;
#pragma unroll
      for (int kk = 0; kk < 2; kk++) {
        bfrag af[4], bf_[4];
#pragma unroll
        for (int mt = 0; mt < 4; mt++)
          af[mt] = *(const bfrag*)(Qs[i] + (size_t)(tb + mt * 16 + lrow) * HD_ + kk * 32 + quad * 8);
#pragma unroll
        for (int nt = 0; nt < 4; nt++)
          bf_[nt] = *(const bfrag*)(Kb + (size_t)(sb + nt * 16 + lrow) * HD_ + kk * 32 + quad * 8);
#pragma unroll
        for (int mt = 0; mt < 4; mt++)
#pragma unroll
          for (int nt = 0; nt < 4; nt++)
            acc[mt][nt] = __builtin_amdgcn_mfma_f32_16x16x32_bf16(af[mt], bf_[nt], acc[mt][nt], 0, 0, 0);
      }
      const float ri = r[i];
      __syncthreads();   // prev PV's ds_reads complete before overwrite
#pragma unroll
      for (int mt = 0; mt < 4; mt++)
#pragma unroll
        for (int nt = 0; nt < 4; nt++)
#pragma unroll
          for (int ii = 0; ii < 4; ii++) {
            const float e = __expf(acc[mt][nt][ii] * 0.25f);
            const int tl = tw * 64 + mt * 16 + quad * 4 + ii;
            const int sl = sw * 64 + nt * 16 + lrow;
            P[tl * 136 + sl] = f2b(ri * e);
            if (i == 0) {
              const int t = blockIdx.x * 128 + tl;
              a1out[((size_t)bh * T_ + t) * T_ + s0 + sl] = e * a1s;
            }
          }
      __syncthreads();   // P ready
#pragma unroll
      for (int kk = 0; kk < 4; kk++) {
        bfrag pf[4], vf[2];
#pragma unroll
        for (int mt = 0; mt < 4; mt++)
          pf[mt] = *(const bfrag*)(P + (tw * 64 + mt * 16 + lrow) * 136 + kk * 32 + quad * 8);
#pragma unroll
        for (int nt = 0; nt < 2; nt++)
          vf[nt] = *(const bfrag*)(Vb + (size_t)(dw * 32 + nt * 16 + lrow) * T_ + s0 + kk * 32 + quad * 8);
#pragma unroll
        for (int mt = 0; mt < 4; mt++)
#pragma unroll
          for (int nt = 0; nt < 2; nt++)
            oacc[mt][nt] = __builtin_amdgcn_mfma_f32_16x16x32_bf16(pf[mt], vf[nt], oacc[mt][nt], 0, 0, 0);
      }
    }
  }
  float* Ob = Opart + (size_t)seg * 2097152 + (size_t)bh * 65536;
#pragma unroll
  for (int mt = 0; mt < 4; mt++)
#pragma unroll
    for (int nt = 0; nt < 2; nt++)
#pragma unroll
      for (int ii = 0; ii < 4; ii++) {
        const int t = tb + mt * 16 + quad * 4 + ii;
        const int dd = dw * 32 + nt * 16 + lrow;
        Ob[(size_t)t * 64 + dd] = oacc[mt][nt][ii];
      }
}

// ---------------------------------------------------------------- partial reduce -> bf16 attn
__global__ __launch_bounds__(256) void reduce_kernel(const float* __restrict__ Op,
                                                     unsigned short* __restrict__ attn) {
  const int flat = blockIdx.x * 256 + threadIdx.x;   // 0..524287
  const int dq = (flat & 15) * 4;
  const int t  = (flat >> 4) & 1023;
  const int bh = flat >> 14;
  const int b = bh >> 4, h = bh & 15;
  const size_t poff = (size_t)bh * 65536 + (size_t)t * 64 + dq;
  float4 s0 = *(const float4*)(Op + poff);
  float4 s1 = *(const float4*)(Op + 2097152 + poff);
  float4 s2 = *(const float4*)(Op + 2 * 2097152 + poff);
  float4 s3 = *(const float4*)(Op + 3 * (size_t)2097152 + poff);
  ushort4 o;
  o.x = f2b(s0.x + s1.x + s2.x + s3.x);
  o.y = f2b(s0.y + s1.y + s2.y + s3.y);
  o.z = f2b(s0.z + s1.z + s2.z + s3.z);
  o.w = f2b(s0.w + s1.w + s2.w + s3.w);
  *(ushort4*)(attn + ((size_t)(b * T_ + t)) * E_ + h * HD_ + dq) = o;
}

// ---------------------------------------------------------------- output projection
__global__ __launch_bounds__(256) void outproj_kernel(
    const unsigned short* __restrict__ Ab, const unsigned short* __restrict__ Wb,
    const float* __restrict__ bias, float* __restrict__ out) {
  __shared__ unsigned short As[128 * 64];
  __shared__ unsigned short Bs[128 * 64];
  const int m0 = blockIdx.y * 128, n0 = blockIdx.x * 128;
  f32x4 acc[4][4];
#pragma unroll
  for (int mt = 0; mt < 4; mt++)
#pragma unroll
    for (int nt = 0; nt < 4; nt++) acc[mt][nt] = (f32x4)0.f;

  mm128_bk64(Ab, Wb, m0, n0, As, Bs, acc);

  const int tid = threadIdx.x, lane = tid & 63, w = tid >> 6;
  const int lrow = lane & 15, quad = lane >> 4;
  const int wm = (w >> 1) * 64, wn = (w & 1) * 64;
  float bv[4];
#pragma unroll
  for (int nt = 0; nt < 4; nt++) bv[nt] = bias[n0 + wn + nt * 16 + lrow];
#pragma unroll
  for (int mt = 0; mt < 4; mt++)
#pragma unroll
    for (int nt = 0; nt < 4; nt++)
#pragma unroll
      for (int ii = 0; ii < 4; ii++) {
        const int m = m0 + wm + mt * 16 + quad * 4 + ii;
        const int n = n0 + wn + nt * 16 + lrow;
        out[(size_t)m * E_ + n] = acc[mt][nt][ii] + bv[nt];
      }
}

// ---------------------------------------------------------------- launcher
extern "C" void kernel_launch(void* const* d_in, const int* in_sizes, int n_in,
                              void* d_out, int out_size, void* d_ws, size_t ws_size,
                              hipStream_t stream) {
  const float* q1f  = (const float*)d_in[0];
  const float* q2f  = (const float*)d_in[1];
  const float* keyf = (const float*)d_in[2];
  const float* valf = (const float*)d_in[3];
  const float* Wq  = (const float*)d_in[4];  const float* bq  = (const float*)d_in[5];
  const float* Wq2 = (const float*)d_in[6];  const float* bq2 = (const float*)d_in[7];
  const float* Wq3 = (const float*)d_in[8];  const float* bq3 = (const float*)d_in[9];
  const float* Wk  = (const float*)d_in[10]; const float* bk  = (const float*)d_in[11];
  const float* Wv  = (const float*)d_in[12]; const float* bv  = (const float*)d_in[13];
  const float* Wo  = (const float*)d_in[14]; const float* bo  = (const float*)d_in[15];

  char* ws = (char*)d_ws;
  const size_t MB = 1024 * 1024;
  unsigned short* xq1  = (unsigned short*)(ws + 0 * MB);
  unsigned short* xq2  = (unsigned short*)(ws + 4 * MB);
  unsigned short* xkey = (unsigned short*)(ws + 8 * MB);
  unsigned short* xval = (unsigned short*)(ws + 12 * MB);
  unsigned short* wq   = (unsigned short*)(ws + 16 * MB);
  unsigned short* wq2  = (unsigned short*)(ws + 18 * MB);
  unsigned short* wq3  = (unsigned short*)(ws + 20 * MB);
  unsigned short* wk   = (unsigned short*)(ws + 22 * MB);
  unsigned short* wv   = (unsigned short*)(ws + 24 * MB);
  unsigned short* wo   = (unsigned short*)(ws + 26 * MB);
  unsigned short* Qh1  = (unsigned short*)(ws + 28 * MB);
  unsigned short* Qh2  = (unsigned short*)(ws + 32 * MB);
  unsigned short* Qh3  = (unsigned short*)(ws + 36 * MB);
  unsigned short* Kh   = (unsigned short*)(ws + 40 * MB);
  unsigned short* Vt   = (unsigned short*)(ws + 44 * MB);
  unsigned short* attn = (unsigned short*)(ws + 48 * MB);
  float* Opart         = (float*)(ws + 52 * MB);           // 4 x 8MB fp32 partials
  float* Sp            = (float*)(ws + 84 * MB);           // 3*32*64 partial sums

  // 1) fp32 -> bf16
  CvtArgs ca;
  const float* srcs[10] = {q1f, q2f, keyf, valf, Wq, Wq2, Wq3, Wk, Wv, Wo};
  unsigned short* dsts[10] = {xq1, xq2, xkey, xval, wq, wq2, wq3, wk, wv, wo};
  for (int i = 0; i < 10; i++) { ca.src[i] = srcs[i]; ca.dst[i] = dsts[i]; ca.n[i] = (i < 4) ? 2097152 : 1048576; }
  cvt_kernel<<<dim3(2048, 10), 256, 0, stream>>>(ca);

  // 2) projections -> head layouts (V transposed)
  ProjArgs pa;
  const unsigned short* Xs[5] = {xq1, xq2, xkey, xkey, xval};
  const unsigned short* Ws_[5] = {wq, wq2, wq3, wk, wv};
  const float* Bi[5] = {bq, bq2, bq3, bk, bv};
  unsigned short* Ds[5] = {Qh1, Qh2, Qh3, Kh, Vt};
  for (int i = 0; i < 5; i++) { pa.X[i] = Xs[i]; pa.W[i] = Ws_[i]; pa.bias[i] = Bi[i]; pa.dst[i] = Ds[i]; }
  proj_kernel<<<dim3(8, 16, 5), 256, 0, stream>>>(pa);

  // 3) global softmax partial sums (no atomics)
  attn_sums_kernel<<<dim3(8, 8, BH_), 256, 0, stream>>>(Qh1, Qh2, Qh3, Kh, Sp);

  // 4) attention: a1 + fp32 partial O per s-segment (1024 blocks)
  float* out = (float*)d_out;
  attn_main_kernel<<<dim3(8, 4, BH_), 256, 0, stream>>>(Qh1, Qh2, Qh3, Kh, Vt, Sp,
                                                        out + 2097152, Opart);

  // 5) reduce partials -> bf16 attn
  reduce_kernel<<<dim3(2048), 256, 0, stream>>>(Opart, attn);

  // 6) output projection
  outproj_kernel<<<dim3(8, 16), 256, 0, stream>>>(attn, wo, bo, out);
}